// Round 1
// baseline (135.654 us; speedup 1.0000x reference)
//
#include <hip/hip_runtime.h>
#include <stdint.h>

#define B_ 2
#define L_ 2048
#define D_ 512
#define H_ 8
#define DH_ 64

using frag8 = __attribute__((ext_vector_type(8))) short;   // 8 bf16 in 4 VGPRs
using f32x4 = __attribute__((ext_vector_type(4))) float;   // MFMA accumulator

__device__ __forceinline__ unsigned short f2bf(float f) {
    unsigned int u = __float_as_uint(f);
    u += 0x7fffu + ((u >> 16) & 1u);      // RNE
    return (unsigned short)(u >> 16);
}

__device__ __forceinline__ void gl2lds16(const void* g, void* lds) {
    __builtin_amdgcn_global_load_lds((const __attribute__((address_space(1))) void*)g,
                                     (__attribute__((address_space(3))) void*)lds,
                                     16, 0, 0);
}

// ---------------- prep: fp32 -> bf16 conversions ----------------
__global__ __launch_bounds__(256) void cvt_kernel(
    const float* __restrict__ qx, const float* __restrict__ kx, const float* __restrict__ vx,
    const float* __restrict__ Wq, const float* __restrict__ Wk, const float* __restrict__ Wv,
    const float* __restrict__ Wo,
    unsigned short* qb, unsigned short* kb, unsigned short* vb,
    unsigned short* wqb, unsigned short* wkb, unsigned short* wvb, unsigned short* wob)
{
    const long NA = (long)B_ * L_ * D_;     // 2097152
    const long NW = (long)D_ * D_;          // 262144
    const long total4 = (3 * NA + 4 * NW) / 4;
    long q4 = (long)blockIdx.x * 256 + threadIdx.x;
    if (q4 >= total4) return;
    long i = q4 * 4;
    const float* src; unsigned short* dst; long off;
    if (i < NA)            { src = qx; dst = qb; off = i; }
    else if (i < 2 * NA)   { src = kx; dst = kb; off = i - NA; }
    else if (i < 3 * NA)   { src = vx; dst = vb; off = i - 2 * NA; }
    else {
        long j = i - 3 * NA;
        int w = (int)(j / NW);
        off = j - (long)w * NW;
        src = (w == 0) ? Wq : (w == 1) ? Wk : (w == 2) ? Wv : Wo;
        dst = (w == 0) ? wqb : (w == 1) ? wkb : (w == 2) ? wvb : wob;
    }
    float4 v = *(const float4*)(src + off);
    ushort4 o;
    o.x = f2bf(v.x); o.y = f2bf(v.y); o.z = f2bf(v.z); o.w = f2bf(v.w);
    *(ushort4*)(dst + off) = o;
}

// ---------------- mask: energy -> additive key mask ----------------
__global__ __launch_bounds__(256) void mask_kernel(const float* __restrict__ ec,
                                                   float* __restrict__ mk)
{
    int i = blockIdx.x * 256 + threadIdx.x;      // 0..B*L-1
    if (i >= B_ * L_) return;
    const float4* p4 = (const float4*)(ec + (long)i * 16);
    float s = 0.0f;
#pragma unroll
    for (int j = 0; j < 4; ++j) {
        float4 v = p4[j];
        s += fabsf(v.x) + fabsf(v.y) + fabsf(v.z) + fabsf(v.w);
    }
    float energy = s * (1.0f / 16.0f);
    mk[i] = (energy > 0.1f) ? 0.0f : -1e9f;       // forward of straight-through = hard
}

// ---------------- GEMM: C[M,N] = A[M,K] * W[N,K]^T + bias ----------------
struct GemmPtrs {
    const unsigned short* A[3];
    const unsigned short* W[3];
    const float* bias[3];
    void* C[3];
};

template<int OUTF32>
__global__ __launch_bounds__(256) void gemm_kernel(GemmPtrs gp, int M, int N, int K)
{
    const int z = blockIdx.z;
    const unsigned short* __restrict__ A = gp.A[z];
    const unsigned short* __restrict__ W = gp.W[z];
    const float* __restrict__ bias = gp.bias[z];

    __shared__ __align__(16) unsigned short As[128 * 32];
    __shared__ __align__(16) unsigned short Bs[128 * 32];

    const int tid  = threadIdx.x;
    const int lane = tid & 63;
    const int wave = tid >> 6;
    const int hi   = lane >> 4;
    const int ln   = lane & 15;
    const int wr   = wave >> 1;
    const int wc   = wave & 1;

    const long mBase = (long)blockIdx.y * 128;
    const long nBase = (long)blockIdx.x * 128;

    f32x4 acc[4][4];
#pragma unroll
    for (int m = 0; m < 4; ++m)
#pragma unroll
        for (int n = 0; n < 4; ++n) acc[m][n] = (f32x4){0.f, 0.f, 0.f, 0.f};

    for (int kt = 0; kt < K; kt += 32) {
        // stage A,W tiles: 512 chunks of 16B each, 2 per thread per matrix.
        // LDS is linear; the XOR swizzle (col ^ ((row>>1)&3)) is applied on the
        // GLOBAL source so ds_read side can de-swizzle (both-sides rule).
#pragma unroll
        for (int i = 0; i < 2; ++i) {
            int cb  = i * 256 + wave * 64;          // wave-uniform chunk base
            int c   = cb + lane;
            int row = c >> 2, col = c & 3;
            int scol = col ^ ((row >> 1) & 3);
            gl2lds16(A + (mBase + row) * K + kt + scol * 8, As + cb * 8);
            gl2lds16(W + (nBase + row) * K + kt + scol * 8, Bs + cb * 8);
        }
        __syncthreads();   // compiler drains vmcnt(0) before s_barrier -> LDS ready

        frag8 af[4], bfr[4];
#pragma unroll
        for (int m = 0; m < 4; ++m) {
            int row = wr * 64 + m * 16 + ln;
            int ch  = hi ^ ((row >> 1) & 3);
            af[m] = *(const frag8*)(As + row * 32 + ch * 8);
        }
#pragma unroll
        for (int n = 0; n < 4; ++n) {
            int row = wc * 64 + n * 16 + ln;
            int ch  = hi ^ ((row >> 1) & 3);
            bfr[n] = *(const frag8*)(Bs + row * 32 + ch * 8);
        }
#pragma unroll
        for (int m = 0; m < 4; ++m)
#pragma unroll
            for (int n = 0; n < 4; ++n)
                acc[m][n] = __builtin_amdgcn_mfma_f32_16x16x32_bf16(af[m], bfr[n], acc[m][n], 0, 0, 0);
        __syncthreads();   // protect LDS before next stage
    }

    // epilogue: C/D layout col=lane&15, row=4*(lane>>4)+reg (m89-verified)
#pragma unroll
    for (int m = 0; m < 4; ++m) {
#pragma unroll
        for (int n = 0; n < 4; ++n) {
            long col = nBase + wc * 64 + n * 16 + ln;
            float bv = bias[col];
#pragma unroll
            for (int j = 0; j < 4; ++j) {
                long row = mBase + wr * 64 + m * 16 + hi * 4 + j;
                float v = acc[m][n][j] + bv;
                if (OUTF32) ((float*)gp.C[z])[row * N + col] = v;
                else        ((unsigned short*)gp.C[z])[row * N + col] = f2bf(v);
            }
        }
    }
}

// ---------------- fused flash attention ----------------
// grid: (L/64 q-tiles, B*H). 256 threads = 4 waves, each wave owns 16 q rows.
// S^T = mfma(K_half, Q): lane holds q = lane&15 -> softmax is lane-local per q.
__global__ __launch_bounds__(256) void attn_kernel(
    const unsigned short* __restrict__ Qg, const unsigned short* __restrict__ Kg,
    const unsigned short* __restrict__ Vg, const float* __restrict__ mk,
    unsigned short* __restrict__ Og)
{
    const int tid  = threadIdx.x;
    const int lane = tid & 63;
    const int wave = tid >> 6;
    const int hi   = lane >> 4;
    const int ln   = lane & 15;

    const int bh = blockIdx.y;
    const int b  = bh >> 3, h = bh & 7;
    const long base = ((long)b * L_) * D_ + h * DH_;
    const unsigned short* Qb = Qg + base;
    const unsigned short* Kb = Kg + base;
    const unsigned short* Vb = Vg + base;
    const float* mkb = mk + (long)b * L_;

    __shared__ __align__(16) unsigned short Ks[32 * 64];
    __shared__ __align__(16) unsigned short Vs[32 * 64];

    const int q0 = blockIdx.x * 64 + wave * 16;

    // Q fragments (B operand): col(q)=ln, k(dh) = ks*32 + hi*8 + j  (same map as A)
    frag8 qf[2];
#pragma unroll
    for (int ks = 0; ks < 2; ++ks)
        qf[ks] = *(const frag8*)(Qb + (long)(q0 + ln) * D_ + ks * 32 + hi * 8);

    f32x4 o[4];
#pragma unroll
    for (int g = 0; g < 4; ++g) o[g] = (f32x4){0.f, 0.f, 0.f, 0.f};
    float m_run = -__builtin_inff();
    float l_run = 0.0f;

    // staging: 256 chunks (32 key rows x 8 chunks of 16B), 1 per thread,
    // source-swizzled col^(row&7) so swizzled ds_read is bank-conflict-free
    const int srow = tid >> 3;
    const int scol = (tid & 7) ^ (srow & 7);
    const int cb   = wave * 64;

    for (int t = 0; t < L_ / 32; ++t) {
        const long krow = (long)(t * 32 + srow) * D_;
        gl2lds16(Kb + krow + scol * 8, Ks + cb * 8);
        gl2lds16(Vb + krow + scol * 8, Vs + cb * 8);
        __syncthreads();

        // S^T for 32 keys: two 16-key halves, 2 dh-ksteps each
        f32x4 s0 = (f32x4){0.f,0.f,0.f,0.f}, s1 = (f32x4){0.f,0.f,0.f,0.f};
#pragma unroll
        for (int ks = 0; ks < 2; ++ks) {
            int c0 = (ks * 4 + hi) ^ (ln & 7);
            frag8 k0 = *(const frag8*)(Ks + ln * 64 + c0 * 8);
            frag8 k1 = *(const frag8*)(Ks + (16 + ln) * 64 + c0 * 8);
            s0 = __builtin_amdgcn_mfma_f32_16x16x32_bf16(k0, qf[ks], s0, 0, 0, 0);
            s1 = __builtin_amdgcn_mfma_f32_16x16x32_bf16(k1, qf[ks], s1, 0, 0, 0);
        }

        // scale + key mask. lane's keys: 4*hi+r (half0), 16+4*hi+r (half1)
        float4 mk0 = *(const float4*)(mkb + t * 32 + 4 * hi);
        float4 mk1 = *(const float4*)(mkb + t * 32 + 16 + 4 * hi);
        float sc[8];
        sc[0] = s0[0] * 0.125f + mk0.x;  sc[1] = s0[1] * 0.125f + mk0.y;
        sc[2] = s0[2] * 0.125f + mk0.z;  sc[3] = s0[3] * 0.125f + mk0.w;
        sc[4] = s1[0] * 0.125f + mk1.x;  sc[5] = s1[1] * 0.125f + mk1.y;
        sc[6] = s1[2] * 0.125f + mk1.z;  sc[7] = s1[3] * 0.125f + mk1.w;

        // online softmax, per q = ln (reduce across the 4 hi-groups)
        float tmax = fmaxf(fmaxf(fmaxf(sc[0], sc[1]), fmaxf(sc[2], sc[3])),
                           fmaxf(fmaxf(sc[4], sc[5]), fmaxf(sc[6], sc[7])));
        tmax = fmaxf(tmax, __shfl_xor(tmax, 16));
        tmax = fmaxf(tmax, __shfl_xor(tmax, 32));
        float m_new = fmaxf(m_run, tmax);
        float alpha = __expf(m_run - m_new);
        m_run = m_new;

        float p[8];
        float psum = 0.0f;
#pragma unroll
        for (int j = 0; j < 8; ++j) { p[j] = __expf(sc[j] - m_new); psum += p[j]; }
        psum += __shfl_xor(psum, 16);
        psum += __shfl_xor(psum, 32);
        l_run = l_run * alpha + psum;

        // rescale o (rows q=4*hi+j need alpha of lane 4*hi+j)
        float a0 = __shfl(alpha, 4 * hi + 0);
        float a1 = __shfl(alpha, 4 * hi + 1);
        float a2 = __shfl(alpha, 4 * hi + 2);
        float a3 = __shfl(alpha, 4 * hi + 3);
#pragma unroll
        for (int g = 0; g < 4; ++g) {
            o[g][0] *= a0; o[g][1] *= a1; o[g][2] *= a2; o[g][3] *= a3;
        }

        // P fragment: key = 4*hi + (j&3) + 16*(j>>2)  (natural from s0/s1)
        frag8 pf;
#pragma unroll
        for (int j = 0; j < 8; ++j) pf[j] = (short)f2bf(p[j]);

        // PV: V loaded with the SAME k(key) map as P -> permutation-invariant
#pragma unroll
        for (int g = 0; g < 4; ++g) {
            frag8 vf;
#pragma unroll
            for (int j = 0; j < 8; ++j) {
                int key = 4 * hi + (j & 3) + 16 * (j >> 2);
                int dh  = g * 16 + ln;
                int adr = key * 64 + (((dh >> 3) ^ (key & 7)) << 3) + (dh & 7);
                vf[j] = (short)Vs[adr];
            }
            o[g] = __builtin_amdgcn_mfma_f32_16x16x32_bf16(pf, vf, o[g], 0, 0, 0);
        }
        __syncthreads();
    }

    // normalize + store (out row q = q0 + 4*hi + j, col dh = g*16 + ln)
    float li = 1.0f / l_run;
    float i0 = __shfl(li, 4 * hi + 0);
    float i1 = __shfl(li, 4 * hi + 1);
    float i2 = __shfl(li, 4 * hi + 2);
    float i3 = __shfl(li, 4 * hi + 3);
#pragma unroll
    for (int g = 0; g < 4; ++g) {
        const float iv[4] = {i0, i1, i2, i3};
#pragma unroll
        for (int j = 0; j < 4; ++j) {
            long idx = ((long)b * L_ + q0 + 4 * hi + j) * D_ + h * DH_ + g * 16 + ln;
            Og[idx] = f2bf(o[g][j] * iv[j]);
        }
    }
}

// ---------------- launch ----------------
extern "C" void kernel_launch(void* const* d_in, const int* in_sizes, int n_in,
                              void* d_out, int out_size, void* d_ws, size_t ws_size,
                              hipStream_t stream)
{
    const float* qx = (const float*)d_in[0];
    const float* kx = (const float*)d_in[1];
    const float* vx = (const float*)d_in[2];
    const float* ec = (const float*)d_in[3];
    const float* Wq = (const float*)d_in[4];
    const float* bq = (const float*)d_in[5];
    const float* Wk = (const float*)d_in[6];
    const float* bk = (const float*)d_in[7];
    const float* Wv = (const float*)d_in[8];
    const float* bv = (const float*)d_in[9];
    const float* Wo = (const float*)d_in[10];
    const float* bo = (const float*)d_in[11];
    float* out = (float*)d_out;

    const long NA = (long)B_ * L_ * D_;   // 2097152
    const long NW = (long)D_ * D_;        // 262144

    unsigned short* qb  = (unsigned short*)d_ws;
    unsigned short* kb  = qb + NA;
    unsigned short* vb  = kb + NA;
    unsigned short* wqb = vb + NA;
    unsigned short* wkb = wqb + NW;
    unsigned short* wvb = wkb + NW;
    unsigned short* wob = wvb + NW;
    unsigned short* Qp  = wob + NW;
    unsigned short* Kp  = Qp + NA;
    unsigned short* Vp  = Kp + NA;
    unsigned short* Ap  = qb;             // alias: qb dead after QKV GEMM
    float*          mk  = (float*)(Vp + NA);

    const long total4 = (3 * NA + 4 * NW) / 4;
    cvt_kernel<<<dim3((unsigned)((total4 + 255) / 256)), dim3(256), 0, stream>>>(
        qx, kx, vx, Wq, Wk, Wv, Wo, qb, kb, vb, wqb, wkb, wvb, wob);
    mask_kernel<<<dim3(16), dim3(256), 0, stream>>>(ec, mk);

    GemmPtrs g1;
    g1.A[0] = qb;  g1.A[1] = kb;  g1.A[2] = vb;
    g1.W[0] = wqb; g1.W[1] = wkb; g1.W[2] = wvb;
    g1.bias[0] = bq; g1.bias[1] = bk; g1.bias[2] = bv;
    g1.C[0] = Qp; g1.C[1] = Kp; g1.C[2] = Vp;
    gemm_kernel<0><<<dim3(4, 32, 3), dim3(256), 0, stream>>>(g1, B_ * L_, D_, D_);

    attn_kernel<<<dim3(L_ / 64, B_ * H_), dim3(256), 0, stream>>>(Qp, Kp, Vp, mk, Ap);

    GemmPtrs g2;
    for (int i = 0; i < 3; ++i) { g2.A[i] = Ap; g2.W[i] = wob; g2.bias[i] = bo; g2.C[i] = out; }
    gemm_kernel<1><<<dim3(4, 32, 1), dim3(256), 0, stream>>>(g2, B_ * L_, D_, D_);
}

// Round 2
// 111.931 us; speedup vs baseline: 1.2119x; 1.2119x over previous
//
#include <hip/hip_runtime.h>
#include <stdint.h>

#define B_ 2
#define L_ 2048
#define D_ 512
#define H_ 8
#define DH_ 64

using frag8 = __attribute__((ext_vector_type(8))) short;   // 8 bf16 in 4 VGPRs
using bf4   = __attribute__((ext_vector_type(4))) short;   // 4 bf16 (one b64)
using f32x4 = __attribute__((ext_vector_type(4))) float;   // MFMA accumulator

__device__ __forceinline__ unsigned short f2bf(float f) {
    unsigned int u = __float_as_uint(f);
    u += 0x7fffu + ((u >> 16) & 1u);      // RNE
    return (unsigned short)(u >> 16);
}

__device__ __forceinline__ void gl2lds16(const void* g, void* lds) {
    __builtin_amdgcn_global_load_lds((const __attribute__((address_space(1))) void*)g,
                                     (__attribute__((address_space(3))) void*)lds,
                                     16, 0, 0);
}

// ---------------- prep: fp32 -> bf16 conversions ----------------
__global__ __launch_bounds__(256) void cvt_kernel(
    const float* __restrict__ qx, const float* __restrict__ kx, const float* __restrict__ vx,
    const float* __restrict__ Wq, const float* __restrict__ Wk, const float* __restrict__ Wv,
    const float* __restrict__ Wo,
    unsigned short* qb, unsigned short* kb, unsigned short* vb,
    unsigned short* wqb, unsigned short* wkb, unsigned short* wvb, unsigned short* wob)
{
    const long NA = (long)B_ * L_ * D_;
    const long NW = (long)D_ * D_;
    const long total4 = (3 * NA + 4 * NW) / 4;
    long q4 = (long)blockIdx.x * 256 + threadIdx.x;
    if (q4 >= total4) return;
    long i = q4 * 4;
    const float* src; unsigned short* dst; long off;
    if (i < NA)            { src = qx; dst = qb; off = i; }
    else if (i < 2 * NA)   { src = kx; dst = kb; off = i - NA; }
    else if (i < 3 * NA)   { src = vx; dst = vb; off = i - 2 * NA; }
    else {
        long j = i - 3 * NA;
        int w = (int)(j / NW);
        off = j - (long)w * NW;
        src = (w == 0) ? Wq : (w == 1) ? Wk : (w == 2) ? Wv : Wo;
        dst = (w == 0) ? wqb : (w == 1) ? wkb : (w == 2) ? wvb : wob;
    }
    float4 v = *(const float4*)(src + off);
    ushort4 o;
    o.x = f2bf(v.x); o.y = f2bf(v.y); o.z = f2bf(v.z); o.w = f2bf(v.w);
    *(ushort4*)(dst + off) = o;
}

// ---------------- mask: energy -> additive key mask ----------------
__global__ __launch_bounds__(256) void mask_kernel(const float* __restrict__ ec,
                                                   float* __restrict__ mk)
{
    int i = blockIdx.x * 256 + threadIdx.x;
    if (i >= B_ * L_) return;
    const float4* p4 = (const float4*)(ec + (long)i * 16);
    float s = 0.0f;
#pragma unroll
    for (int j = 0; j < 4; ++j) {
        float4 v = p4[j];
        s += fabsf(v.x) + fabsf(v.y) + fabsf(v.z) + fabsf(v.w);
    }
    float energy = s * (1.0f / 16.0f);
    mk[i] = (energy > 0.1f) ? 0.0f : -1e9f;
}

// ---------------- GEMM: C[M,N] = A[M,K] * W[N,K]^T + bias ----------------
struct GemmPtrs {
    const unsigned short* A[2];
    const unsigned short* W[2];
    const float* bias[2];
    void* C[2];
};

template<int OUTF32, int ROWBIAS>
__global__ __launch_bounds__(256) void gemm_kernel(GemmPtrs gp, int M, int N, int K)
{
    const int z = blockIdx.z;
    const unsigned short* __restrict__ A = gp.A[z];
    const unsigned short* __restrict__ W = gp.W[z];
    const float* __restrict__ bias = gp.bias[z];

    __shared__ __align__(16) unsigned short As[128 * 32];
    __shared__ __align__(16) unsigned short Bs[128 * 32];

    const int tid  = threadIdx.x;
    const int lane = tid & 63;
    const int wave = tid >> 6;
    const int hi   = lane >> 4;
    const int ln   = lane & 15;
    const int wr   = wave >> 1;
    const int wc   = wave & 1;

    const long mBase = (long)blockIdx.y * 128;
    const long nBase = (long)blockIdx.x * 128;

    f32x4 acc[4][4];
#pragma unroll
    for (int m = 0; m < 4; ++m)
#pragma unroll
        for (int n = 0; n < 4; ++n) acc[m][n] = (f32x4){0.f, 0.f, 0.f, 0.f};

    for (int kt = 0; kt < K; kt += 32) {
#pragma unroll
        for (int i = 0; i < 2; ++i) {
            int cb  = i * 256 + wave * 64;
            int c   = cb + lane;
            int row = c >> 2, col = c & 3;
            int scol = col ^ ((row >> 1) & 3);
            gl2lds16(A + (mBase + row) * K + kt + scol * 8, As + cb * 8);
            gl2lds16(W + (nBase + row) * K + kt + scol * 8, Bs + cb * 8);
        }
        __syncthreads();

        frag8 af[4], bfr[4];
#pragma unroll
        for (int m = 0; m < 4; ++m) {
            int row = wr * 64 + m * 16 + ln;
            int ch  = hi ^ ((row >> 1) & 3);
            af[m] = *(const frag8*)(As + row * 32 + ch * 8);
        }
#pragma unroll
        for (int n = 0; n < 4; ++n) {
            int row = wc * 64 + n * 16 + ln;
            int ch  = hi ^ ((row >> 1) & 3);
            bfr[n] = *(const frag8*)(Bs + row * 32 + ch * 8);
        }
#pragma unroll
        for (int m = 0; m < 4; ++m)
#pragma unroll
            for (int n = 0; n < 4; ++n)
                acc[m][n] = __builtin_amdgcn_mfma_f32_16x16x32_bf16(af[m], bfr[n], acc[m][n], 0, 0, 0);
        __syncthreads();
    }

#pragma unroll
    for (int m = 0; m < 4; ++m) {
#pragma unroll
        for (int n = 0; n < 4; ++n) {
            long col = nBase + wc * 64 + n * 16 + ln;
            float bcol = ROWBIAS ? 0.0f : bias[col];
#pragma unroll
            for (int j = 0; j < 4; ++j) {
                long row = mBase + wr * 64 + m * 16 + hi * 4 + j;
                float v = acc[m][n][j] + (ROWBIAS ? bias[row] : bcol);
                if (OUTF32) ((float*)gp.C[z])[row * N + col] = v;
                else        ((unsigned short*)gp.C[z])[row * N + col] = f2bf(v);
            }
        }
    }
}

// ---------------- fused flash attention ----------------
// grid (L/64, B*H), 256 thr = 4 waves x 16 q-rows. 64-key tiles, double-buffered
// K ([key][dh], chunk-swizzled) and V^T ([dh][key], chunk-swizzled) in LDS.
__global__ __launch_bounds__(256) void attn_kernel(
    const unsigned short* __restrict__ Qg, const unsigned short* __restrict__ Kg,
    const unsigned short* __restrict__ Vt, const float* __restrict__ mkg,
    unsigned short* __restrict__ Og)
{
    const int tid  = threadIdx.x;
    const int lane = tid & 63;
    const int wave = tid >> 6;
    const int hi   = lane >> 4;
    const int ln   = lane & 15;

    const int bh = blockIdx.y;
    const int b  = bh >> 3, h = bh & 7;
    const unsigned short* Qb = Qg + ((long)b * L_) * D_ + h * DH_;
    const unsigned short* Kb = Kg + ((long)b * L_) * D_ + h * DH_;
    const unsigned short* Vb = Vt + (long)(h * DH_) * (B_ * L_) + (long)b * L_;
    const float* mkb = mkg + (long)b * L_;

    __shared__ __align__(16) unsigned short Ks[2][64 * 64];
    __shared__ __align__(16) unsigned short Vs[2][64 * 64];
    __shared__ __align__(16) float mskl[L_];

    const int q0 = blockIdx.x * 64 + wave * 16;

    frag8 qf[2];
#pragma unroll
    for (int ks = 0; ks < 2; ++ks)
        qf[ks] = *(const frag8*)(Qb + (long)(q0 + ln) * D_ + ks * 32 + hi * 8);

    // stage the full mask row once (8KB)
#pragma unroll
    for (int i = 0; i < 2; ++i) {
        int cb = i * 256 + wave * 64;
        gl2lds16(mkb + (cb + lane) * 4, &mskl[cb * 4]);
    }

    // per-tile staging: K[key][dh] with 16B chunk swizzle c^(key&7);
    //                   V^T[dh][key] with 16B chunk swizzle c^(dh&7)
#define STAGE(T, BUF) do {                                                        \
    _Pragma("unroll")                                                             \
    for (int i_ = 0; i_ < 2; ++i_) {                                              \
        int cb_ = i_ * 256 + wave * 64;                                           \
        int cl_ = cb_ + lane;                                                     \
        int r_  = cl_ >> 3, c_ = cl_ & 7;                                         \
        gl2lds16(Kb + (long)((T) * 64 + r_) * D_ + ((c_ ^ (r_ & 7)) << 3),        \
                 &Ks[BUF][cb_ * 8]);                                              \
        gl2lds16(Vb + (long)r_ * (B_ * L_) + (T) * 64 + ((c_ ^ (r_ & 7)) << 3),   \
                 &Vs[BUF][cb_ * 8]);                                              \
    }                                                                             \
} while (0)

    STAGE(0, 0);
    __syncthreads();

    f32x4 o[4];
#pragma unroll
    for (int g = 0; g < 4; ++g) o[g] = (f32x4){0.f, 0.f, 0.f, 0.f};
    float m_run = -__builtin_inff();
    float l_run = 0.0f;

    for (int t = 0; t < L_ / 64; ++t) {
        const int buf = t & 1;
        if (t < L_ / 64 - 1) STAGE(t + 1, buf ^ 1);

        const unsigned short* Kl = Ks[buf];
        const unsigned short* Vl = Vs[buf];

        // ---- QK^T: S^T quarters, lane holds q=ln, keys sh*16+4*hi+r ----
        f32x4 sv[4];
#pragma unroll
        for (int sh = 0; sh < 4; ++sh) sv[sh] = (f32x4){0.f, 0.f, 0.f, 0.f};
        __builtin_amdgcn_s_setprio(1);
#pragma unroll
        for (int sh = 0; sh < 4; ++sh) {
            int key = sh * 16 + ln;
#pragma unroll
            for (int ks = 0; ks < 2; ++ks) {
                frag8 kf = *(const frag8*)(Kl + key * 64 + (((ks * 4 + hi) ^ (ln & 7)) << 3));
                sv[sh] = __builtin_amdgcn_mfma_f32_16x16x32_bf16(kf, qf[ks], sv[sh], 0, 0, 0);
            }
        }
        __builtin_amdgcn_s_setprio(0);

        // ---- scale + mask ----
        float sc[16];
#pragma unroll
        for (int sh = 0; sh < 4; ++sh) {
            float4 m4 = *(const float4*)(&mskl[t * 64 + sh * 16 + 4 * hi]);
            sc[sh * 4 + 0] = sv[sh][0] * 0.125f + m4.x;
            sc[sh * 4 + 1] = sv[sh][1] * 0.125f + m4.y;
            sc[sh * 4 + 2] = sv[sh][2] * 0.125f + m4.z;
            sc[sh * 4 + 3] = sv[sh][3] * 0.125f + m4.w;
        }

        // ---- online softmax (per q = ln) ----
        float tmax = sc[0];
#pragma unroll
        for (int j = 1; j < 16; ++j) tmax = fmaxf(tmax, sc[j]);
        tmax = fmaxf(tmax, __shfl_xor(tmax, 16));
        tmax = fmaxf(tmax, __shfl_xor(tmax, 32));

        if (!__all(tmax <= m_run)) {
            float m_new = fmaxf(m_run, tmax);
            float alpha = __expf(m_run - m_new);
            float a0 = __shfl(alpha, 4 * hi + 0);
            float a1 = __shfl(alpha, 4 * hi + 1);
            float a2 = __shfl(alpha, 4 * hi + 2);
            float a3 = __shfl(alpha, 4 * hi + 3);
#pragma unroll
            for (int g = 0; g < 4; ++g) {
                o[g][0] *= a0; o[g][1] *= a1; o[g][2] *= a2; o[g][3] *= a3;
            }
            l_run *= alpha;
            m_run = m_new;
        }

        float p[16];
        float ps = 0.0f;
#pragma unroll
        for (int j = 0; j < 16; ++j) { p[j] = __expf(sc[j] - m_run); ps += p[j]; }
        ps += __shfl_xor(ps, 16);
        ps += __shfl_xor(ps, 32);
        l_run += ps;

        // ---- pack P: pf0 keys {4hi+r, 16+4hi+r}, pf1 keys {32+4hi+r, 48+4hi+r} ----
        frag8 pf0, pf1;
#pragma unroll
        for (int r = 0; r < 4; ++r) {
            pf0[r]     = (short)f2bf(p[r]);
            pf0[4 + r] = (short)f2bf(p[4 + r]);
            pf1[r]     = (short)f2bf(p[8 + r]);
            pf1[4 + r] = (short)f2bf(p[12 + r]);
        }

        // ---- PV: vectorized b64 reads from V^T, same key map as P ----
        __builtin_amdgcn_s_setprio(1);
#pragma unroll
        for (int g = 0; g < 4; ++g) {
            int dh   = g * 16 + ln;
            int rowb = dh * 64;
            int x    = dh & 7;
            int sub  = (hi & 1) << 2;
            int ch   = hi >> 1;
            bf4 a0 = *(const bf4*)(Vl + rowb + (((ch    ) ^ x) << 3) + sub);
            bf4 a1 = *(const bf4*)(Vl + rowb + (((ch + 2) ^ x) << 3) + sub);
            bf4 a2 = *(const bf4*)(Vl + rowb + (((ch + 4) ^ x) << 3) + sub);
            bf4 a3 = *(const bf4*)(Vl + rowb + (((ch + 6) ^ x) << 3) + sub);
            frag8 vf0 = __builtin_shufflevector(a0, a1, 0, 1, 2, 3, 4, 5, 6, 7);
            frag8 vf1 = __builtin_shufflevector(a2, a3, 0, 1, 2, 3, 4, 5, 6, 7);
            o[g] = __builtin_amdgcn_mfma_f32_16x16x32_bf16(pf0, vf0, o[g], 0, 0, 0);
            o[g] = __builtin_amdgcn_mfma_f32_16x16x32_bf16(pf1, vf1, o[g], 0, 0, 0);
        }
        __builtin_amdgcn_s_setprio(0);

        __syncthreads();
    }
#undef STAGE

    // ---- normalize + store ----
    float li = 1.0f / l_run;
    float i0 = __shfl(li, 4 * hi + 0);
    float i1 = __shfl(li, 4 * hi + 1);
    float i2 = __shfl(li, 4 * hi + 2);
    float i3 = __shfl(li, 4 * hi + 3);
#pragma unroll
    for (int g = 0; g < 4; ++g) {
        const float iv[4] = {i0, i1, i2, i3};
#pragma unroll
        for (int j = 0; j < 4; ++j) {
            long idx = ((long)b * L_ + q0 + 4 * hi + j) * D_ + h * DH_ + g * 16 + ln;
            Og[idx] = f2bf(o[g][j] * iv[j]);
        }
    }
}

// ---------------- launch ----------------
extern "C" void kernel_launch(void* const* d_in, const int* in_sizes, int n_in,
                              void* d_out, int out_size, void* d_ws, size_t ws_size,
                              hipStream_t stream)
{
    const float* qx = (const float*)d_in[0];
    const float* kx = (const float*)d_in[1];
    const float* vx = (const float*)d_in[2];
    const float* ec = (const float*)d_in[3];
    const float* Wq = (const float*)d_in[4];
    const float* bq = (const float*)d_in[5];
    const float* Wk = (const float*)d_in[6];
    const float* bk = (const float*)d_in[7];
    const float* Wv = (const float*)d_in[8];
    const float* bv = (const float*)d_in[9];
    const float* Wo = (const float*)d_in[10];
    const float* bo = (const float*)d_in[11];
    float* out = (float*)d_out;

    const long NA = (long)B_ * L_ * D_;
    const long NW = (long)D_ * D_;

    unsigned short* qb  = (unsigned short*)d_ws;
    unsigned short* kb  = qb + NA;
    unsigned short* vb  = kb + NA;
    unsigned short* wqb = vb + NA;
    unsigned short* wkb = wqb + NW;
    unsigned short* wvb = wkb + NW;
    unsigned short* wob = wvb + NW;
    unsigned short* Qp  = wob + NW;
    unsigned short* Kp  = Qp + NA;
    unsigned short* Vtp = Kp + NA;       // V^T: [D][B*L]
    unsigned short* Ap  = qb;            // alias: qb dead after Q GEMM
    float*          mk  = (float*)(Vtp + NA);

    const long total4 = (3 * NA + 4 * NW) / 4;
    cvt_kernel<<<dim3((unsigned)((total4 + 255) / 256)), dim3(256), 0, stream>>>(
        qx, kx, vx, Wq, Wk, Wv, Wo, qb, kb, vb, wqb, wkb, wvb, wob);
    mask_kernel<<<dim3(16), dim3(256), 0, stream>>>(ec, mk);

    // Q, K projections: [4096,512] = x[4096,512] @ W[512,512]^T
    GemmPtrs g1;
    g1.A[0] = qb;  g1.A[1] = kb;
    g1.W[0] = wqb; g1.W[1] = wkb;
    g1.bias[0] = bq; g1.bias[1] = bk;
    g1.C[0] = Qp; g1.C[1] = Kp;
    gemm_kernel<0, 0><<<dim3(4, 32, 2), dim3(256), 0, stream>>>(g1, B_ * L_, D_, D_);

    // V^T = Wv * v_x^T : [512, 4096], row-bias bv
    GemmPtrs gv;
    gv.A[0] = wvb; gv.W[0] = vb; gv.bias[0] = bv; gv.C[0] = Vtp;
    gv.A[1] = wvb; gv.W[1] = vb; gv.bias[1] = bv; gv.C[1] = Vtp;
    gemm_kernel<0, 1><<<dim3(32, 4, 1), dim3(256), 0, stream>>>(gv, D_, B_ * L_, D_);

    attn_kernel<<<dim3(L_ / 64, B_ * H_), dim3(256), 0, stream>>>(Qp, Kp, Vtp, mk, Ap);

    // output projection: f32 out
    GemmPtrs g2;
    g2.A[0] = Ap; g2.W[0] = wob; g2.bias[0] = bo; g2.C[0] = out;
    g2.A[1] = Ap; g2.W[1] = wob; g2.bias[1] = bo; g2.C[1] = out;
    gemm_kernel<1, 0><<<dim3(4, 32, 1), dim3(256), 0, stream>>>(g2, B_ * L_, D_, D_);
}

// Round 3
// 79.932 us; speedup vs baseline: 1.6971x; 1.4003x over previous
//
#include <hip/hip_runtime.h>
#include <stdint.h>

#define B_ 2
#define L_ 2048
#define D_ 512
#define H_ 8
#define DH_ 64

using frag8 = __attribute__((ext_vector_type(8))) short;   // 8 bf16 in 4 VGPRs
using bf4   = __attribute__((ext_vector_type(4))) short;   // 4 bf16 (one b64)
using f32x4 = __attribute__((ext_vector_type(4))) float;   // MFMA accumulator
using u32x4 = __attribute__((ext_vector_type(4))) unsigned int;

#define QSC 0.18033688011112042f   /* 0.125 * log2(e): exp2-domain scale folded into Q */

__device__ __forceinline__ unsigned short f2bf(float f) {
    unsigned int u = __float_as_uint(f);
    u += 0x7fffu + ((u >> 16) & 1u);      // RNE
    return (unsigned short)(u >> 16);
}

__device__ __forceinline__ unsigned int cvtpk(float lo, float hi_) {
    unsigned int r;
    asm("v_cvt_pk_bf16_f32 %0, %1, %2" : "=v"(r) : "v"(lo), "v"(hi_));
    return r;
}

__device__ __forceinline__ void gl2lds16(const void* g, void* lds) {
    __builtin_amdgcn_global_load_lds((const __attribute__((address_space(1))) void*)g,
                                     (__attribute__((address_space(3))) void*)lds,
                                     16, 0, 0);
}

// ---------------- prep: fp32 -> bf16 conversions ----------------
__global__ __launch_bounds__(256) void cvt_kernel(
    const float* __restrict__ qx, const float* __restrict__ kx, const float* __restrict__ vx,
    const float* __restrict__ Wq, const float* __restrict__ Wk, const float* __restrict__ Wv,
    const float* __restrict__ Wo,
    unsigned short* qb, unsigned short* kb, unsigned short* vb,
    unsigned short* wqb, unsigned short* wkb, unsigned short* wvb, unsigned short* wob)
{
    const long NA = (long)B_ * L_ * D_;
    const long NW = (long)D_ * D_;
    const long total4 = (3 * NA + 4 * NW) / 4;
    long q4 = (long)blockIdx.x * 256 + threadIdx.x;
    if (q4 >= total4) return;
    long i = q4 * 4;
    const float* src; unsigned short* dst; long off;
    if (i < NA)            { src = qx; dst = qb; off = i; }
    else if (i < 2 * NA)   { src = kx; dst = kb; off = i - NA; }
    else if (i < 3 * NA)   { src = vx; dst = vb; off = i - 2 * NA; }
    else {
        long j = i - 3 * NA;
        int w = (int)(j / NW);
        off = j - (long)w * NW;
        src = (w == 0) ? Wq : (w == 1) ? Wk : (w == 2) ? Wv : Wo;
        dst = (w == 0) ? wqb : (w == 1) ? wkb : (w == 2) ? wvb : wob;
    }
    float4 v = *(const float4*)(src + off);
    ushort4 o;
    o.x = f2bf(v.x); o.y = f2bf(v.y); o.z = f2bf(v.z); o.w = f2bf(v.w);
    *(ushort4*)(dst + off) = o;
}

// ---------------- mask: energy -> additive key mask (exp2 domain) ----------------
__global__ __launch_bounds__(256) void mask_kernel(const float* __restrict__ ec,
                                                   float* __restrict__ mk)
{
    int i = blockIdx.x * 256 + threadIdx.x;
    if (i >= B_ * L_) return;
    const float4* p4 = (const float4*)(ec + (long)i * 16);
    float s = 0.0f;
#pragma unroll
    for (int j = 0; j < 4; ++j) {
        float4 v = p4[j];
        s += fabsf(v.x) + fabsf(v.y) + fabsf(v.z) + fabsf(v.w);
    }
    float energy = s * (1.0f / 16.0f);
    mk[i] = (energy > 0.1f) ? 0.0f : -1.0e9f;
}

// ---------------- GEMM: C[M,N] = A[M,K] * W[N,K]^T + bias ----------------
// mode 0: bf16 store; 1: bf16 store scaled by QSC (Q proj); 2: bf16 transposed
// + slot-swizzled store (V^T); 3: f32 store (output proj).
struct GemmArgs { const unsigned short* A; const unsigned short* W;
                  const float* bias; void* C; int mode; };

template<int BM, int BN>
__global__ __launch_bounds__(256) void gemm_kernel(GemmArgs a0, GemmArgs a1, GemmArgs a2,
                                                   int M, int N, int K)
{
    GemmArgs ga = blockIdx.z == 0 ? a0 : (blockIdx.z == 1 ? a1 : a2);
    const unsigned short* __restrict__ A = ga.A;
    const unsigned short* __restrict__ W = ga.W;
    const float* __restrict__ bias = ga.bias;

    constexpr int MF = BM / 32;
    constexpr int NF = BN / 32;

    __shared__ __align__(16) unsigned short As[BM * 64];
    __shared__ __align__(16) unsigned short Bs[BN * 64];

    const int tid  = threadIdx.x;
    const int lane = tid & 63;
    const int wave = tid >> 6;
    const int hi   = lane >> 4;
    const int ln   = lane & 15;
    const int wr   = wave >> 1;
    const int wc   = wave & 1;

    const long mBase = (long)blockIdx.y * BM;
    const long nBase = (long)blockIdx.x * BN;

    f32x4 acc[MF][NF];
#pragma unroll
    for (int m = 0; m < MF; ++m)
#pragma unroll
        for (int n = 0; n < NF; ++n) acc[m][n] = (f32x4){0.f, 0.f, 0.f, 0.f};

    for (int kt = 0; kt < K; kt += 64) {
#pragma unroll
        for (int i = 0; i < BM / 32; ++i) {
            int cl = i * 256 + tid;
            int r = cl >> 3, c = cl & 7, sc = c ^ (r & 7);
            gl2lds16(A + (mBase + r) * K + kt + sc * 8, As + cl * 8);
        }
#pragma unroll
        for (int i = 0; i < BN / 32; ++i) {
            int cl = i * 256 + tid;
            int r = cl >> 3, c = cl & 7, sc = c ^ (r & 7);
            gl2lds16(W + (nBase + r) * K + kt + sc * 8, Bs + cl * 8);
        }
        __syncthreads();

        frag8 af[2][MF], bfr[2][NF];
#pragma unroll
        for (int kk = 0; kk < 2; ++kk) {
#pragma unroll
            for (int m = 0; m < MF; ++m) {
                int row = wr * (BM / 2) + m * 16 + ln;
                int c = (kk * 4 + hi) ^ (row & 7);
                af[kk][m] = *(const frag8*)(As + row * 64 + c * 8);
            }
#pragma unroll
            for (int n = 0; n < NF; ++n) {
                int row = wc * (BN / 2) + n * 16 + ln;
                int c = (kk * 4 + hi) ^ (row & 7);
                bfr[kk][n] = *(const frag8*)(Bs + row * 64 + c * 8);
            }
        }
        __builtin_amdgcn_s_setprio(1);
#pragma unroll
        for (int kk = 0; kk < 2; ++kk)
#pragma unroll
            for (int m = 0; m < MF; ++m)
#pragma unroll
                for (int n = 0; n < NF; ++n)
                    acc[m][n] = __builtin_amdgcn_mfma_f32_16x16x32_bf16(af[kk][m], bfr[kk][n], acc[m][n], 0, 0, 0);
        __builtin_amdgcn_s_setprio(0);
        __syncthreads();
    }

    const int mode = ga.mode;
#pragma unroll
    for (int m = 0; m < MF; ++m) {
#pragma unroll
        for (int n = 0; n < NF; ++n) {
            long col = nBase + wc * (BN / 2) + n * 16 + ln;
            float bv = bias[col];
#pragma unroll
            for (int j = 0; j < 4; ++j) {
                long row = mBase + wr * (BM / 2) + m * 16 + hi * 4 + j;
                float v = acc[m][n][j] + bv;
                if (mode == 3) {
                    ((float*)ga.C)[row * N + col] = v;
                } else if (mode == 2) {
                    int dh = (int)col & 63;
                    int swv = ((dh & 7) << 1) | ((dh >> 3) & 1);
                    long nt = (row & ~63L) | (long)(((((int)(row >> 2)) & 15) ^ swv) << 2) | (row & 3);
                    ((unsigned short*)ga.C)[col * (long)(B_ * L_) + nt] = f2bf(v);
                } else {
                    if (mode == 1) v *= QSC;
                    ((unsigned short*)ga.C)[row * N + col] = f2bf(v);
                }
            }
        }
    }
}

// ---------------- fused flash attention ----------------
// grid (L/64, B*H), 512 thr = 8 waves. Waves 0-3 (group 0) process even 64-key
// tiles, waves 4-7 (group 1) odd tiles; each group double-buffers its own K/V
// in LDS; partial (m,l,o) merged through LDS at the end. Q pre-scaled by
// 0.125*log2e -> softmax in exp2 domain. V^T pre-swizzled in global (staged
// linearly; conflict-free b64 reads).
__global__ __launch_bounds__(512, 4) void attn_kernel(
    const unsigned short* __restrict__ Qg, const unsigned short* __restrict__ Kg,
    const unsigned short* __restrict__ Vt, const float* __restrict__ mkg,
    unsigned short* __restrict__ Og)
{
    const int tid  = threadIdx.x;
    const int lane = tid & 63;
    const int wave = tid >> 6;
    const int grp  = wave >> 2;
    const int wq   = wave & 3;
    const int gtid = tid & 255;
    const int hi   = lane >> 4;
    const int ln   = lane & 15;

    const int bh = blockIdx.y;
    const int b  = bh >> 3, h = bh & 7;
    const unsigned short* Qb = Qg + ((long)b * L_) * D_ + h * DH_;
    const unsigned short* Kb = Kg + ((long)b * L_) * D_ + h * DH_;
    const unsigned short* Vb = Vt + (long)(h * DH_) * (B_ * L_) + (long)b * L_;
    const float* mkb = mkg + (long)b * L_;

    __shared__ __align__(16) char smem[65536];
    unsigned short* KsG = (unsigned short*)(smem + grp * 32768);
    unsigned short* VsG = (unsigned short*)(smem + grp * 32768 + 16384);

    const int q0 = blockIdx.x * 64 + wq * 16;

    frag8 qf[2];
#pragma unroll
    for (int ks = 0; ks < 2; ++ks)
        qf[ks] = *(const frag8*)(Qb + (long)(q0 + ln) * D_ + ks * 32 + hi * 8);

    // hoisted PV slot offsets (V^T global pre-swizzle: slot s stored at s^sw)
    const int sw  = ((ln & 7) << 1) | ((ln >> 3) & 1);
    const int sl0 = ((hi     ) ^ sw) << 2;
    const int sl1 = ((hi + 4 ) ^ sw) << 2;
    const int sl2 = ((hi + 8 ) ^ sw) << 2;
    const int sl3 = ((hi + 12) ^ sw) << 2;

#define STAGE(TT, BUF) do {                                                     \
    _Pragma("unroll")                                                           \
    for (int c2_ = 0; c2_ < 2; ++c2_) {                                         \
        int cl_ = c2_ * 256 + gtid;                                             \
        int r_ = cl_ >> 3, c_ = cl_ & 7;                                        \
        gl2lds16(Kb + (long)((TT) * 64 + r_) * D_ + ((c_ ^ (r_ & 7)) << 3),     \
                 KsG + (BUF) * 4096 + cl_ * 8);                                 \
        gl2lds16(Vb + (long)r_ * (B_ * L_) + (TT) * 64 + (c_ << 3),             \
                 VsG + (BUF) * 4096 + cl_ * 8);                                 \
    }                                                                           \
} while (0)

    STAGE(grp, 0);
    __syncthreads();

    f32x4 o[4];
#pragma unroll
    for (int g = 0; g < 4; ++g) o[g] = (f32x4){0.f, 0.f, 0.f, 0.f};
    float m_run = -__builtin_inff();
    float l_run = 0.0f;

    for (int i = 0; i < 16; ++i) {
        const int T = 2 * i + grp;
        const int buf = i & 1;

        // mask prefetch (L2-hot, latency hidden under QK^T)
        float4 m40 = *(const float4*)(mkb + T * 64 +      4 * hi);
        float4 m41 = *(const float4*)(mkb + T * 64 + 16 + 4 * hi);
        float4 m42 = *(const float4*)(mkb + T * 64 + 32 + 4 * hi);
        float4 m43 = *(const float4*)(mkb + T * 64 + 48 + 4 * hi);

        if (i < 15) STAGE(2 * (i + 1) + grp, buf ^ 1);

        const unsigned short* Kl = KsG + buf * 4096;
        const unsigned short* Vl = VsG + buf * 4096;

        // ---- QK^T: S^T quarters, lane holds q=ln, keys sh*16+4*hi+r ----
        f32x4 sv[4];
#pragma unroll
        for (int sh = 0; sh < 4; ++sh) sv[sh] = (f32x4){0.f, 0.f, 0.f, 0.f};
        __builtin_amdgcn_s_setprio(1);
#pragma unroll
        for (int sh = 0; sh < 4; ++sh) {
            int key = sh * 16 + ln;
#pragma unroll
            for (int ks = 0; ks < 2; ++ks) {
                frag8 kf = *(const frag8*)(Kl + key * 64 + (((ks * 4 + hi) ^ (ln & 7)) << 3));
                sv[sh] = __builtin_amdgcn_mfma_f32_16x16x32_bf16(kf, qf[ks], sv[sh], 0, 0, 0);
            }
        }
        __builtin_amdgcn_s_setprio(0);

        // ---- mask add (scale already folded into Q) ----
        float sc[16];
        sc[0]  = sv[0][0] + m40.x; sc[1]  = sv[0][1] + m40.y;
        sc[2]  = sv[0][2] + m40.z; sc[3]  = sv[0][3] + m40.w;
        sc[4]  = sv[1][0] + m41.x; sc[5]  = sv[1][1] + m41.y;
        sc[6]  = sv[1][2] + m41.z; sc[7]  = sv[1][3] + m41.w;
        sc[8]  = sv[2][0] + m42.x; sc[9]  = sv[2][1] + m42.y;
        sc[10] = sv[2][2] + m42.z; sc[11] = sv[2][3] + m42.w;
        sc[12] = sv[3][0] + m43.x; sc[13] = sv[3][1] + m43.w == 0 ? sv[3][1] + m43.y : sv[3][1] + m43.y;
        sc[13] = sv[3][1] + m43.y;
        sc[14] = sv[3][2] + m43.z; sc[15] = sv[3][3] + m43.w;

        // ---- online softmax (per q = ln), exp2 domain ----
        float t0 = fmaxf(fmaxf(sc[0], sc[1]), sc[2]);
        float t1 = fmaxf(fmaxf(sc[3], sc[4]), sc[5]);
        float t2 = fmaxf(fmaxf(sc[6], sc[7]), sc[8]);
        float t3 = fmaxf(fmaxf(sc[9], sc[10]), sc[11]);
        float t4 = fmaxf(fmaxf(sc[12], sc[13]), sc[14]);
        float tmax = fmaxf(fmaxf(fmaxf(t0, t1), fmaxf(t2, t3)), fmaxf(t4, sc[15]));
        tmax = fmaxf(tmax, __shfl_xor(tmax, 16));
        tmax = fmaxf(tmax, __shfl_xor(tmax, 32));

        if (!__all(tmax <= m_run)) {
            float m_new = fmaxf(m_run, tmax);
            float alpha = __builtin_amdgcn_exp2f(m_run - m_new);
            float a0 = __shfl(alpha, 4 * hi + 0);
            float a1 = __shfl(alpha, 4 * hi + 1);
            float a2 = __shfl(alpha, 4 * hi + 2);
            float a3 = __shfl(alpha, 4 * hi + 3);
#pragma unroll
            for (int g = 0; g < 4; ++g) {
                o[g][0] *= a0; o[g][1] *= a1; o[g][2] *= a2; o[g][3] *= a3;
            }
            l_run *= alpha;
            m_run = m_new;
        }

        float p[16];
#pragma unroll
        for (int j = 0; j < 16; ++j) p[j] = __builtin_amdgcn_exp2f(sc[j] - m_run);
        float s01 = (p[0] + p[1]) + (p[2] + p[3]);
        float s23 = (p[4] + p[5]) + (p[6] + p[7]);
        float s45 = (p[8] + p[9]) + (p[10] + p[11]);
        float s67 = (p[12] + p[13]) + (p[14] + p[15]);
        float ps = (s01 + s23) + (s45 + s67);
        ps += __shfl_xor(ps, 16);
        ps += __shfl_xor(ps, 32);
        l_run += ps;

        // ---- pack P via v_cvt_pk_bf16_f32 ----
        union PU { u32x4 u; frag8 f; } p0u, p1u;
        p0u.u = (u32x4){cvtpk(p[0], p[1]),  cvtpk(p[2], p[3]),
                        cvtpk(p[4], p[5]),  cvtpk(p[6], p[7])};
        p1u.u = (u32x4){cvtpk(p[8], p[9]),  cvtpk(p[10], p[11]),
                        cvtpk(p[12], p[13]), cvtpk(p[14], p[15])};

        // ---- PV: conflict-free b64 reads from pre-swizzled V^T ----
        __builtin_amdgcn_s_setprio(1);
#pragma unroll
        for (int g = 0; g < 4; ++g) {
            int rowb = (g * 16 + ln) * 64;
            bf4 a0 = *(const bf4*)(Vl + rowb + sl0);
            bf4 a1 = *(const bf4*)(Vl + rowb + sl1);
            bf4 a2 = *(const bf4*)(Vl + rowb + sl2);
            bf4 a3 = *(const bf4*)(Vl + rowb + sl3);
            frag8 vf0 = __builtin_shufflevector(a0, a1, 0, 1, 2, 3, 4, 5, 6, 7);
            frag8 vf1 = __builtin_shufflevector(a2, a3, 0, 1, 2, 3, 4, 5, 6, 7);
            o[g] = __builtin_amdgcn_mfma_f32_16x16x32_bf16(p0u.f, vf0, o[g], 0, 0, 0);
            o[g] = __builtin_amdgcn_mfma_f32_16x16x32_bf16(p1u.f, vf1, o[g], 0, 0, 0);
        }
        __builtin_amdgcn_s_setprio(0);

        __syncthreads();
    }
#undef STAGE

    // ---- merge group 1 partials into group 0, write out ----
    float* oX = (float*)smem;                       // [64][68] padded f32
    float* mX = (float*)(smem + 64 * 68 * 4);       // [64]
    float* lX = mX + 64;

    if (grp == 1) {
#pragma unroll
        for (int g = 0; g < 4; ++g)
#pragma unroll
            for (int j = 0; j < 4; ++j)
                oX[(wq * 16 + 4 * hi + j) * 68 + g * 16 + ln] = o[g][j];
        if (hi == 0) { mX[wq * 16 + ln] = m_run; lX[wq * 16 + ln] = l_run; }
    }
    __syncthreads();
    if (grp == 0) {
#pragma unroll
        for (int j = 0; j < 4; ++j) {
            int q = 4 * hi + j;
            float mA = __shfl(m_run, q);
            float lA = __shfl(l_run, q);
            float mB = mX[wq * 16 + q];
            float lB = lX[wq * 16 + q];
            float mm = fmaxf(mA, mB);
            float aA = __builtin_amdgcn_exp2f(mA - mm);
            float aB = __builtin_amdgcn_exp2f(mB - mm);
            float inv = 1.0f / (lA * aA + lB * aB);
            aA *= inv; aB *= inv;
#pragma unroll
            for (int g = 0; g < 4; ++g) {
                float v = o[g][j] * aA + oX[(wq * 16 + q) * 68 + g * 16 + ln] * aB;
                long idx = ((long)b * L_ + q0 + q) * D_ + h * DH_ + g * 16 + ln;
                Og[idx] = f2bf(v);
            }
        }
    }
}

// ---------------- launch ----------------
extern "C" void kernel_launch(void* const* d_in, const int* in_sizes, int n_in,
                              void* d_out, int out_size, void* d_ws, size_t ws_size,
                              hipStream_t stream)
{
    const float* qx = (const float*)d_in[0];
    const float* kx = (const float*)d_in[1];
    const float* vx = (const float*)d_in[2];
    const float* ec = (const float*)d_in[3];
    const float* Wq = (const float*)d_in[4];
    const float* bq = (const float*)d_in[5];
    const float* Wk = (const float*)d_in[6];
    const float* bk = (const float*)d_in[7];
    const float* Wv = (const float*)d_in[8];
    const float* bv = (const float*)d_in[9];
    const float* Wo = (const float*)d_in[10];
    const float* bo = (const float*)d_in[11];
    float* out = (float*)d_out;

    const long NA = (long)B_ * L_ * D_;
    const long NW = (long)D_ * D_;

    unsigned short* qb  = (unsigned short*)d_ws;
    unsigned short* kb  = qb + NA;
    unsigned short* vb  = kb + NA;
    unsigned short* wqb = vb + NA;
    unsigned short* wkb = wqb + NW;
    unsigned short* wvb = wkb + NW;
    unsigned short* wob = wvb + NW;
    unsigned short* Qp  = wob + NW;
    unsigned short* Kp  = Qp + NA;
    unsigned short* Vtp = Kp + NA;       // V^T: [D][B*L], slot-swizzled
    unsigned short* Ap  = qb;            // alias: qb dead after Q GEMM
    float*          mk  = (float*)(Vtp + NA);

    const long total4 = (3 * NA + 4 * NW) / 4;
    cvt_kernel<<<dim3((unsigned)((total4 + 255) / 256)), dim3(256), 0, stream>>>(
        qx, kx, vx, Wq, Wk, Wv, Wo, qb, kb, vb, wqb, wkb, wvb, wob);
    mask_kernel<<<dim3(16), dim3(256), 0, stream>>>(ec, mk);

    // fused QKV projections (768 blocks): Q scaled, K plain, V transposed+swizzled
    GemmArgs zq = {qb, wqb, bq, Qp, 1};
    GemmArgs zk = {kb, wkb, bk, Kp, 0};
    GemmArgs zv = {vb, wvb, bv, Vtp, 2};
    gemm_kernel<64, 128><<<dim3(4, 64, 3), dim3(256), 0, stream>>>(zq, zk, zv, B_ * L_, D_, D_);

    attn_kernel<<<dim3(L_ / 64, B_ * H_), dim3(512), 0, stream>>>(Qp, Kp, Vtp, mk, Ap);

    // output projection, f32 out (512 blocks)
    GemmArgs zo = {Ap, wob, bo, out, 3};
    gemm_kernel<64, 64><<<dim3(8, 64, 1), dim3(256), 0, stream>>>(zo, zo, zo, B_ * L_, D_, D_);
}

// Round 4
// 78.557 us; speedup vs baseline: 1.7268x; 1.0175x over previous
//
#include <hip/hip_runtime.h>
#include <stdint.h>

#define B_ 2
#define L_ 2048
#define D_ 512
#define H_ 8
#define DH_ 64

using frag8 = __attribute__((ext_vector_type(8))) short;   // 8 bf16 in 4 VGPRs
using bf4   = __attribute__((ext_vector_type(4))) short;   // 4 bf16 (one b64)
using f32x4 = __attribute__((ext_vector_type(4))) float;   // MFMA accumulator
using u32x4 = __attribute__((ext_vector_type(4))) unsigned int;

#define QSC 0.18033688011112042f   /* 0.125 * log2(e): exp2-domain scale folded into Q */

__device__ __forceinline__ unsigned short f2bf(float f) {
    unsigned int u = __float_as_uint(f);
    u += 0x7fffu + ((u >> 16) & 1u);      // RNE
    return (unsigned short)(u >> 16);
}

__device__ __forceinline__ unsigned int cvtpk(float lo, float hi_) {
    unsigned int r;
    asm("v_cvt_pk_bf16_f32 %0, %1, %2" : "=v"(r) : "v"(lo), "v"(hi_));
    return r;
}

__device__ __forceinline__ void gl2lds16(const void* g, void* lds) {
    __builtin_amdgcn_global_load_lds((const __attribute__((address_space(1))) void*)g,
                                     (__attribute__((address_space(3))) void*)lds,
                                     16, 0, 0);
}

// ---------------- prep: fp32 -> bf16 conversions + energy mask ----------------
__global__ __launch_bounds__(256) void cvt_mask_kernel(
    const float* __restrict__ qx, const float* __restrict__ kx, const float* __restrict__ vx,
    const float* __restrict__ Wq, const float* __restrict__ Wk, const float* __restrict__ Wv,
    const float* __restrict__ Wo, const float* __restrict__ ec,
    unsigned short* qb, unsigned short* kb, unsigned short* vb,
    unsigned short* wqb, unsigned short* wkb, unsigned short* wvb, unsigned short* wob,
    float* __restrict__ mk)
{
    const long NA = (long)B_ * L_ * D_;
    const long NW = (long)D_ * D_;
    const long total4 = (3 * NA + 4 * NW) / 4;
    long q4 = (long)blockIdx.x * 256 + threadIdx.x;
    if (q4 < total4) {
        long i = q4 * 4;
        const float* src; unsigned short* dst; long off;
        if (i < NA)            { src = qx; dst = qb; off = i; }
        else if (i < 2 * NA)   { src = kx; dst = kb; off = i - NA; }
        else if (i < 3 * NA)   { src = vx; dst = vb; off = i - 2 * NA; }
        else {
            long j = i - 3 * NA;
            int w = (int)(j / NW);
            off = j - (long)w * NW;
            src = (w == 0) ? Wq : (w == 1) ? Wk : (w == 2) ? Wv : Wo;
            dst = (w == 0) ? wqb : (w == 1) ? wkb : (w == 2) ? wvb : wob;
        }
        float4 v = *(const float4*)(src + off);
        ushort4 o;
        o.x = f2bf(v.x); o.y = f2bf(v.y); o.z = f2bf(v.z); o.w = f2bf(v.w);
        *(ushort4*)(dst + off) = o;
    } else {
        long i = q4 - total4;                     // 0..B*L-1 (tail blocks)
        if (i < B_ * L_) {
            const float4* p4 = (const float4*)(ec + i * 16);
            float s = 0.0f;
#pragma unroll
            for (int j = 0; j < 4; ++j) {
                float4 v = p4[j];
                s += fabsf(v.x) + fabsf(v.y) + fabsf(v.z) + fabsf(v.w);
            }
            float energy = s * (1.0f / 16.0f);
            mk[i] = (energy > 0.1f) ? 0.0f : -1.0e9f;
        }
    }
}

// ---------------- GEMM: C[M,N] = A[M,K] * W[N,K]^T + bias ----------------
// Double-buffered LDS (2-phase pipeline) + bijective XCD-chunked block swizzle.
// mode 0: bf16 store; 1: bf16 * QSC (Q proj); 2: bf16 transposed + slot-swizzled
// (V^T); 3: f32 store (output proj).
struct GemmArgs { const unsigned short* A; const unsigned short* W;
                  const float* bias; void* C; int mode; };

template<int BM, int BN>
__global__ __launch_bounds__(256) void gemm_kernel(GemmArgs a0, GemmArgs a1, GemmArgs a2,
                                                   int M, int N, int K)
{
    // XCD-chunked swizzle (grid size divisible by 8 by construction)
    const int nwg = gridDim.x * gridDim.y * gridDim.z;
    int flat = blockIdx.x + gridDim.x * (blockIdx.y + gridDim.y * blockIdx.z);
    int swz  = (flat & 7) * (nwg >> 3) + (flat >> 3);
    const int bx = swz % gridDim.x;
    int t2 = swz / gridDim.x;
    const int by = t2 % gridDim.y;
    const int bz = t2 / gridDim.y;

    GemmArgs ga = bz == 0 ? a0 : (bz == 1 ? a1 : a2);
    const unsigned short* __restrict__ A = ga.A;
    const unsigned short* __restrict__ W = ga.W;
    const float* __restrict__ bias = ga.bias;

    constexpr int MF = BM / 32;
    constexpr int NF = BN / 32;

    __shared__ __align__(16) unsigned short As[2][BM * 64];
    __shared__ __align__(16) unsigned short Bs[2][BN * 64];

    const int tid  = threadIdx.x;
    const int lane = tid & 63;
    const int wave = tid >> 6;
    const int hi   = lane >> 4;
    const int ln   = lane & 15;
    const int wr   = wave >> 1;
    const int wc   = wave & 1;

    const long mBase = (long)by * BM;
    const long nBase = (long)bx * BN;

    f32x4 acc[MF][NF];
#pragma unroll
    for (int m = 0; m < MF; ++m)
#pragma unroll
        for (int n = 0; n < NF; ++n) acc[m][n] = (f32x4){0.f, 0.f, 0.f, 0.f};

#define GSTAGE(KT, BUF) do {                                                    \
    _Pragma("unroll")                                                           \
    for (int i_ = 0; i_ < BM / 32; ++i_) {                                      \
        int cl_ = i_ * 256 + tid;                                               \
        int r_ = cl_ >> 3, c_ = cl_ & 7, s_ = c_ ^ (r_ & 7);                    \
        gl2lds16(A + (mBase + r_) * K + (KT) + s_ * 8, As[BUF] + cl_ * 8);      \
    }                                                                           \
    _Pragma("unroll")                                                           \
    for (int i_ = 0; i_ < BN / 32; ++i_) {                                      \
        int cl_ = i_ * 256 + tid;                                               \
        int r_ = cl_ >> 3, c_ = cl_ & 7, s_ = c_ ^ (r_ & 7);                    \
        gl2lds16(W + (nBase + r_) * K + (KT) + s_ * 8, Bs[BUF] + cl_ * 8);      \
    }                                                                           \
} while (0)

    GSTAGE(0, 0);
    __syncthreads();

    const int nk = K / 64;
    for (int t = 0; t < nk; ++t) {
        const int buf = t & 1;
        if (t + 1 < nk) GSTAGE((t + 1) * 64, buf ^ 1);

        frag8 af[2][MF], bfr[2][NF];
#pragma unroll
        for (int kk = 0; kk < 2; ++kk) {
#pragma unroll
            for (int m = 0; m < MF; ++m) {
                int row = wr * (BM / 2) + m * 16 + ln;
                int c = (kk * 4 + hi) ^ (row & 7);
                af[kk][m] = *(const frag8*)(As[buf] + row * 64 + c * 8);
            }
#pragma unroll
            for (int n = 0; n < NF; ++n) {
                int row = wc * (BN / 2) + n * 16 + ln;
                int c = (kk * 4 + hi) ^ (row & 7);
                bfr[kk][n] = *(const frag8*)(Bs[buf] + row * 64 + c * 8);
            }
        }
        __builtin_amdgcn_s_setprio(1);
#pragma unroll
        for (int kk = 0; kk < 2; ++kk)
#pragma unroll
            for (int m = 0; m < MF; ++m)
#pragma unroll
                for (int n = 0; n < NF; ++n)
                    acc[m][n] = __builtin_amdgcn_mfma_f32_16x16x32_bf16(af[kk][m], bfr[kk][n], acc[m][n], 0, 0, 0);
        __builtin_amdgcn_s_setprio(0);
        __syncthreads();   // next buf staged + this buf's reads complete
    }
#undef GSTAGE

    const int mode = ga.mode;
#pragma unroll
    for (int m = 0; m < MF; ++m) {
#pragma unroll
        for (int n = 0; n < NF; ++n) {
            long col = nBase + wc * (BN / 2) + n * 16 + ln;
            float bv = bias[col];
#pragma unroll
            for (int j = 0; j < 4; ++j) {
                long row = mBase + wr * (BM / 2) + m * 16 + hi * 4 + j;
                float v = acc[m][n][j] + bv;
                if (mode == 3) {
                    ((float*)ga.C)[row * N + col] = v;
                } else if (mode == 2) {
                    int dh = (int)col & 63;
                    int swv = ((dh & 7) << 1) | ((dh >> 3) & 1);
                    long nt = (row & ~63L) | (long)(((((int)(row >> 2)) & 15) ^ swv) << 2) | (row & 3);
                    ((unsigned short*)ga.C)[col * (long)(B_ * L_) + nt] = f2bf(v);
                } else {
                    if (mode == 1) v *= QSC;
                    ((unsigned short*)ga.C)[row * N + col] = f2bf(v);
                }
            }
        }
    }
}

// ---------------- fused flash attention ----------------
// grid (L/64, B*H), 512 thr = 8 waves. Waves 0-3 (group 0) process even 64-key
// tiles, waves 4-7 (group 1) odd tiles; each group double-buffers its own K/V
// in LDS; partial (m,l,o) merged through LDS at the end. Q pre-scaled by
// 0.125*log2e -> softmax in exp2 domain. V^T pre-swizzled in global (staged
// linearly; conflict-free b64 reads).
__global__ __launch_bounds__(512, 4) void attn_kernel(
    const unsigned short* __restrict__ Qg, const unsigned short* __restrict__ Kg,
    const unsigned short* __restrict__ Vt, const float* __restrict__ mkg,
    unsigned short* __restrict__ Og)
{
    const int tid  = threadIdx.x;
    const int lane = tid & 63;
    const int wave = tid >> 6;
    const int grp  = wave >> 2;
    const int wq   = wave & 3;
    const int gtid = tid & 255;
    const int hi   = lane >> 4;
    const int ln   = lane & 15;

    const int bh = blockIdx.y;
    const int b  = bh >> 3, h = bh & 7;
    const unsigned short* Qb = Qg + ((long)b * L_) * D_ + h * DH_;
    const unsigned short* Kb = Kg + ((long)b * L_) * D_ + h * DH_;
    const unsigned short* Vb = Vt + (long)(h * DH_) * (B_ * L_) + (long)b * L_;
    const float* mkb = mkg + (long)b * L_;

    __shared__ __align__(16) char smem[65536];
    unsigned short* KsG = (unsigned short*)(smem + grp * 32768);
    unsigned short* VsG = (unsigned short*)(smem + grp * 32768 + 16384);

    const int q0 = blockIdx.x * 64 + wq * 16;

    frag8 qf[2];
#pragma unroll
    for (int ks = 0; ks < 2; ++ks)
        qf[ks] = *(const frag8*)(Qb + (long)(q0 + ln) * D_ + ks * 32 + hi * 8);

    // hoisted PV slot offsets (V^T global pre-swizzle: slot s stored at s^sw)
    const int sw  = ((ln & 7) << 1) | ((ln >> 3) & 1);
    const int sl0 = ((hi     ) ^ sw) << 2;
    const int sl1 = ((hi + 4 ) ^ sw) << 2;
    const int sl2 = ((hi + 8 ) ^ sw) << 2;
    const int sl3 = ((hi + 12) ^ sw) << 2;

#define STAGE(TT, BUF) do {                                                     \
    _Pragma("unroll")                                                           \
    for (int c2_ = 0; c2_ < 2; ++c2_) {                                         \
        int cl_ = c2_ * 256 + gtid;                                             \
        int r_ = cl_ >> 3, c_ = cl_ & 7;                                        \
        gl2lds16(Kb + (long)((TT) * 64 + r_) * D_ + ((c_ ^ (r_ & 7)) << 3),     \
                 KsG + (BUF) * 4096 + cl_ * 8);                                 \
        gl2lds16(Vb + (long)r_ * (B_ * L_) + (TT) * 64 + (c_ << 3),             \
                 VsG + (BUF) * 4096 + cl_ * 8);                                 \
    }                                                                           \
} while (0)

    STAGE(grp, 0);
    __syncthreads();

    f32x4 o[4];
#pragma unroll
    for (int g = 0; g < 4; ++g) o[g] = (f32x4){0.f, 0.f, 0.f, 0.f};
    float m_run = -__builtin_inff();
    float l_run = 0.0f;

    for (int i = 0; i < 16; ++i) {
        const int T = 2 * i + grp;
        const int buf = i & 1;

        // mask prefetch (L2-hot, latency hidden under QK^T)
        float4 m40 = *(const float4*)(mkb + T * 64 +      4 * hi);
        float4 m41 = *(const float4*)(mkb + T * 64 + 16 + 4 * hi);
        float4 m42 = *(const float4*)(mkb + T * 64 + 32 + 4 * hi);
        float4 m43 = *(const float4*)(mkb + T * 64 + 48 + 4 * hi);

        if (i < 15) STAGE(2 * (i + 1) + grp, buf ^ 1);

        const unsigned short* Kl = KsG + buf * 4096;
        const unsigned short* Vl = VsG + buf * 4096;

        // ---- QK^T: S^T quarters, lane holds q=ln, keys sh*16+4*hi+r ----
        f32x4 sv[4];
#pragma unroll
        for (int sh = 0; sh < 4; ++sh) sv[sh] = (f32x4){0.f, 0.f, 0.f, 0.f};
        __builtin_amdgcn_s_setprio(1);
#pragma unroll
        for (int sh = 0; sh < 4; ++sh) {
            int key = sh * 16 + ln;
#pragma unroll
            for (int ks = 0; ks < 2; ++ks) {
                frag8 kf = *(const frag8*)(Kl + key * 64 + (((ks * 4 + hi) ^ (ln & 7)) << 3));
                sv[sh] = __builtin_amdgcn_mfma_f32_16x16x32_bf16(kf, qf[ks], sv[sh], 0, 0, 0);
            }
        }
        __builtin_amdgcn_s_setprio(0);

        // ---- mask add (scale already folded into Q) ----
        float sc[16];
        sc[0]  = sv[0][0] + m40.x; sc[1]  = sv[0][1] + m40.y;
        sc[2]  = sv[0][2] + m40.z; sc[3]  = sv[0][3] + m40.w;
        sc[4]  = sv[1][0] + m41.x; sc[5]  = sv[1][1] + m41.y;
        sc[6]  = sv[1][2] + m41.z; sc[7]  = sv[1][3] + m41.w;
        sc[8]  = sv[2][0] + m42.x; sc[9]  = sv[2][1] + m42.y;
        sc[10] = sv[2][2] + m42.z; sc[11] = sv[2][3] + m42.w;
        sc[12] = sv[3][0] + m43.x; sc[13] = sv[3][1] + m43.y;
        sc[14] = sv[3][2] + m43.z; sc[15] = sv[3][3] + m43.w;

        // ---- online softmax (per q = ln), exp2 domain ----
        float t0 = fmaxf(fmaxf(sc[0], sc[1]), sc[2]);
        float t1 = fmaxf(fmaxf(sc[3], sc[4]), sc[5]);
        float t2 = fmaxf(fmaxf(sc[6], sc[7]), sc[8]);
        float t3 = fmaxf(fmaxf(sc[9], sc[10]), sc[11]);
        float t4 = fmaxf(fmaxf(sc[12], sc[13]), sc[14]);
        float tmax = fmaxf(fmaxf(fmaxf(t0, t1), fmaxf(t2, t3)), fmaxf(t4, sc[15]));
        tmax = fmaxf(tmax, __shfl_xor(tmax, 16));
        tmax = fmaxf(tmax, __shfl_xor(tmax, 32));

        if (!__all(tmax <= m_run)) {
            float m_new = fmaxf(m_run, tmax);
            float alpha = __builtin_amdgcn_exp2f(m_run - m_new);
            float a0 = __shfl(alpha, 4 * hi + 0);
            float a1 = __shfl(alpha, 4 * hi + 1);
            float a2 = __shfl(alpha, 4 * hi + 2);
            float a3 = __shfl(alpha, 4 * hi + 3);
#pragma unroll
            for (int g = 0; g < 4; ++g) {
                o[g][0] *= a0; o[g][1] *= a1; o[g][2] *= a2; o[g][3] *= a3;
            }
            l_run *= alpha;
            m_run = m_new;
        }

        float p[16];
#pragma unroll
        for (int j = 0; j < 16; ++j) p[j] = __builtin_amdgcn_exp2f(sc[j] - m_run);
        float s01 = (p[0] + p[1]) + (p[2] + p[3]);
        float s23 = (p[4] + p[5]) + (p[6] + p[7]);
        float s45 = (p[8] + p[9]) + (p[10] + p[11]);
        float s67 = (p[12] + p[13]) + (p[14] + p[15]);
        float ps = (s01 + s23) + (s45 + s67);
        ps += __shfl_xor(ps, 16);
        ps += __shfl_xor(ps, 32);
        l_run += ps;

        // ---- pack P via v_cvt_pk_bf16_f32 ----
        union PU { u32x4 u; frag8 f; } p0u, p1u;
        p0u.u = (u32x4){cvtpk(p[0], p[1]),  cvtpk(p[2], p[3]),
                        cvtpk(p[4], p[5]),  cvtpk(p[6], p[7])};
        p1u.u = (u32x4){cvtpk(p[8], p[9]),  cvtpk(p[10], p[11]),
                        cvtpk(p[12], p[13]), cvtpk(p[14], p[15])};

        // ---- PV: conflict-free b64 reads from pre-swizzled V^T ----
        __builtin_amdgcn_s_setprio(1);
#pragma unroll
        for (int g = 0; g < 4; ++g) {
            int rowb = (g * 16 + ln) * 64;
            bf4 a0 = *(const bf4*)(Vl + rowb + sl0);
            bf4 a1 = *(const bf4*)(Vl + rowb + sl1);
            bf4 a2 = *(const bf4*)(Vl + rowb + sl2);
            bf4 a3 = *(const bf4*)(Vl + rowb + sl3);
            frag8 vf0 = __builtin_shufflevector(a0, a1, 0, 1, 2, 3, 4, 5, 6, 7);
            frag8 vf1 = __builtin_shufflevector(a2, a3, 0, 1, 2, 3, 4, 5, 6, 7);
            o[g] = __builtin_amdgcn_mfma_f32_16x16x32_bf16(p0u.f, vf0, o[g], 0, 0, 0);
            o[g] = __builtin_amdgcn_mfma_f32_16x16x32_bf16(p1u.f, vf1, o[g], 0, 0, 0);
        }
        __builtin_amdgcn_s_setprio(0);

        __syncthreads();
    }
#undef STAGE

    // ---- merge group 1 partials into group 0, write out ----
    float* oX = (float*)smem;                       // [64][68] padded f32
    float* mX = (float*)(smem + 64 * 68 * 4);       // [64]
    float* lX = mX + 64;

    if (grp == 1) {
#pragma unroll
        for (int g = 0; g < 4; ++g)
#pragma unroll
            for (int j = 0; j < 4; ++j)
                oX[(wq * 16 + 4 * hi + j) * 68 + g * 16 + ln] = o[g][j];
        if (hi == 0) { mX[wq * 16 + ln] = m_run; lX[wq * 16 + ln] = l_run; }
    }
    __syncthreads();
    if (grp == 0) {
#pragma unroll
        for (int j = 0; j < 4; ++j) {
            int q = 4 * hi + j;
            float mA = __shfl(m_run, q);
            float lA = __shfl(l_run, q);
            float mB = mX[wq * 16 + q];
            float lB = lX[wq * 16 + q];
            float mm = fmaxf(mA, mB);
            float aA = __builtin_amdgcn_exp2f(mA - mm);
            float aB = __builtin_amdgcn_exp2f(mB - mm);
            float inv = 1.0f / (lA * aA + lB * aB);
            aA *= inv; aB *= inv;
#pragma unroll
            for (int g = 0; g < 4; ++g) {
                float v = o[g][j] * aA + oX[(wq * 16 + q) * 68 + g * 16 + ln] * aB;
                long idx = ((long)b * L_ + q0 + q) * D_ + h * DH_ + g * 16 + ln;
                Og[idx] = f2bf(v);
            }
        }
    }
}

// ---------------- launch ----------------
extern "C" void kernel_launch(void* const* d_in, const int* in_sizes, int n_in,
                              void* d_out, int out_size, void* d_ws, size_t ws_size,
                              hipStream_t stream)
{
    const float* qx = (const float*)d_in[0];
    const float* kx = (const float*)d_in[1];
    const float* vx = (const float*)d_in[2];
    const float* ec = (const float*)d_in[3];
    const float* Wq = (const float*)d_in[4];
    const float* bq = (const float*)d_in[5];
    const float* Wk = (const float*)d_in[6];
    const float* bk = (const float*)d_in[7];
    const float* Wv = (const float*)d_in[8];
    const float* bv = (const float*)d_in[9];
    const float* Wo = (const float*)d_in[10];
    const float* bo = (const float*)d_in[11];
    float* out = (float*)d_out;

    const long NA = (long)B_ * L_ * D_;
    const long NW = (long)D_ * D_;

    unsigned short* qb  = (unsigned short*)d_ws;
    unsigned short* kb  = qb + NA;
    unsigned short* vb  = kb + NA;
    unsigned short* wqb = vb + NA;
    unsigned short* wkb = wqb + NW;
    unsigned short* wvb = wkb + NW;
    unsigned short* wob = wvb + NW;
    unsigned short* Qp  = wob + NW;
    unsigned short* Kp  = Qp + NA;
    unsigned short* Vtp = Kp + NA;       // V^T: [D][B*L], slot-swizzled
    unsigned short* Ap  = qb;            // alias: qb dead after Q GEMM
    float*          mk  = (float*)(Vtp + NA);

    const long total4 = (3 * NA + 4 * NW) / 4;
    const long nblk = (total4 + B_ * L_ + 255) / 256;
    cvt_mask_kernel<<<dim3((unsigned)nblk), dim3(256), 0, stream>>>(
        qx, kx, vx, Wq, Wk, Wv, Wo, ec, qb, kb, vb, wqb, wkb, wvb, wob, mk);

    // fused QKV projections (768 blocks): Q scaled, K plain, V transposed+swizzled
    GemmArgs zq = {qb, wqb, bq, Qp, 1};
    GemmArgs zk = {kb, wkb, bk, Kp, 0};
    GemmArgs zv = {vb, wvb, bv, Vtp, 2};
    gemm_kernel<64, 128><<<dim3(4, 64, 3), dim3(256), 0, stream>>>(zq, zk, zv, B_ * L_, D_, D_);

    attn_kernel<<<dim3(L_ / 64, B_ * H_), dim3(512), 0, stream>>>(Qp, Kp, Vtp, mk, Ap);

    // output projection, f32 out (512 blocks)
    GemmArgs zo = {Ap, wob, bo, out, 3};
    gemm_kernel<64, 64><<<dim3(8, 64, 1), dim3(256), 0, stream>>>(zo, zo, zo, B_ * L_, D_, D_);
}